// Round 1
// baseline (351.755 us; speedup 1.0000x reference)
//
#include <hip/hip_runtime.h>

#define D 128
#define GEMM_RPB 8

// ---------------- GEMM: HW = H @ W  (fp32 vector ALU) ----------------
__global__ __launch_bounds__(256) void k_gemm(const float* __restrict__ H,
                                              const float* __restrict__ W,
                                              float* __restrict__ HW, int n) {
    __shared__ float sH[GEMM_RPB][D];
    const int row0 = blockIdx.x * GEMM_RPB;
    const int tid = threadIdx.x;
    {
        int r = tid >> 5;          // 0..7
        int c4 = tid & 31;         // 0..31
        int row = row0 + r;
        float4 v = make_float4(0.f, 0.f, 0.f, 0.f);
        if (row < n) v = reinterpret_cast<const float4*>(H)[(size_t)row * (D / 4) + c4];
        reinterpret_cast<float4*>(&sH[r][0])[c4] = v;
    }
    __syncthreads();
    const int rr = tid >> 5;       // row within block
    const int j4 = tid & 31;       // float4 column group
    const float4* W4 = reinterpret_cast<const float4*>(W);
    float4 acc = make_float4(0.f, 0.f, 0.f, 0.f);
#pragma unroll 8
    for (int k = 0; k < D; ++k) {
        float h = sH[rr][k];
        float4 w = W4[k * (D / 4) + j4];
        acc.x += h * w.x; acc.y += h * w.y; acc.z += h * w.z; acc.w += h * w.w;
    }
    int row = row0 + rr;
    if (row < n) reinterpret_cast<float4*>(HW)[(size_t)row * (D / 4) + j4] = acc;
}

// ---------------- CSR build ----------------
__global__ void k_count(const int* __restrict__ rows, int* __restrict__ cnt, int E) {
    int e = blockIdx.x * blockDim.x + threadIdx.x;
    if (e < E) atomicAdd(&cnt[rows[e]], 1);
}

// single-block exclusive scan over n counts -> ptr[0..n]
__global__ __launch_bounds__(1024) void k_scan(const int* __restrict__ cnt,
                                               int* __restrict__ ptr, int n) {
    __shared__ int wsum[16];
    __shared__ int carry_s;
    const int tid = threadIdx.x;
    const int lane = tid & 63;
    const int wid = tid >> 6;
    if (tid == 0) carry_s = 0;
    __syncthreads();
    for (int base = 0; base < n; base += 1024) {
        int i = base + tid;
        int v = (i < n) ? cnt[i] : 0;
        int inc = v;
#pragma unroll
        for (int off = 1; off < 64; off <<= 1) {
            int t = __shfl_up(inc, off, 64);
            if (lane >= off) inc += t;
        }
        if (lane == 63) wsum[wid] = inc;
        __syncthreads();
        int wexcl = 0;
        for (int w = 0; w < wid; ++w) wexcl += wsum[w];
        int carry = carry_s;
        if (i < n) ptr[i] = carry + wexcl + inc - v;   // exclusive
        __syncthreads();
        if (tid == 1023) carry_s = carry + wexcl + inc; // running total
        __syncthreads();
    }
    if (threadIdx.x == 0) ptr[n] = carry_s;
}

__global__ void k_fill(const int* __restrict__ rows, const int* __restrict__ cols,
                       const float* __restrict__ vals, const int* __restrict__ ptr,
                       int* __restrict__ cursor, int* __restrict__ col_s,
                       float* __restrict__ val_s, int E) {
    int e = blockIdx.x * blockDim.x + threadIdx.x;
    if (e < E) {
        int r = rows[e];
        int p = ptr[r] + atomicAdd(&cursor[r], 1);
        col_s[p] = cols[e];
        val_s[p] = vals[e];
    }
}

// ---------------- Gather SpMM + bias + ReLU ----------------
__global__ __launch_bounds__(128) void k_gather(const float* __restrict__ HW,
                                                const int* __restrict__ ptr,
                                                const int* __restrict__ col_s,
                                                const float* __restrict__ val_s,
                                                const float* __restrict__ bias,
                                                float* __restrict__ out, int n) {
    int r = blockIdx.x;
    if (r >= n) return;
    int j = threadIdx.x;
    int s = ptr[r], e = ptr[r + 1];
    float acc = 0.f;
    for (int t = s; t < e; ++t) {
        int c = col_s[t];
        float v = val_s[t];
        acc += v * HW[(size_t)c * D + j];
    }
    acc += bias[j];
    out[(size_t)r * D + j] = fmaxf(acc, 0.f);
}

// ---------------- Fallback path (small ws): atomic scatter ----------------
__global__ void k_init_bias(const float* __restrict__ bias, float* __restrict__ out, int n) {
    int i = blockIdx.x * blockDim.x + threadIdx.x;
    if (i < n * D) out[i] = bias[i & (D - 1)];
}
__global__ void k_scatter(const float* __restrict__ HW, const int* __restrict__ rows,
                          const int* __restrict__ cols, const float* __restrict__ vals,
                          float* __restrict__ out, int E) {
    int e = blockIdx.x * 2 + (threadIdx.x >> 7);
    int j = threadIdx.x & (D - 1);
    if (e < E) {
        int r = rows[e];
        int c = cols[e];
        float v = vals[e];
        atomicAdd(&out[(size_t)r * D + j], v * HW[(size_t)c * D + j]);
    }
}
__global__ void k_relu(float* __restrict__ out, int n) {
    int i = blockIdx.x * blockDim.x + threadIdx.x;
    if (i < n * D) out[i] = fmaxf(out[i], 0.f);
}

extern "C" void kernel_launch(void* const* d_in, const int* in_sizes, int n_in,
                              void* d_out, int out_size, void* d_ws, size_t ws_size,
                              hipStream_t stream) {
    const float* H         = (const float*)d_in[0];
    const float* W         = (const float*)d_in[1];
    const float* bias      = (const float*)d_in[2];
    const float* edge_vals = (const float*)d_in[3];
    const int*   edge_rows = (const int*)d_in[4];
    const int*   edge_cols = (const int*)d_in[5];
    float* out = (float*)d_out;

    const int n = in_sizes[0] / D;   // 50000
    const int E = in_sizes[3];       // 800000

    char* ws = (char*)d_ws;
    float* HW = (float*)ws;          ws += (size_t)n * D * sizeof(float);
    int* ptr  = (int*)ws;            ws += ((size_t)n + 1) * sizeof(int);
    int* cnt  = (int*)ws;            ws += (size_t)n * sizeof(int);
    int* col_s = (int*)ws;           ws += (size_t)E * sizeof(int);
    float* val_s = (float*)ws;       ws += (size_t)E * sizeof(float);
    size_t need_full = (size_t)(ws - (char*)d_ws);

    k_gemm<<<(n + GEMM_RPB - 1) / GEMM_RPB, 256, 0, stream>>>(H, W, HW, n);

    if (ws_size >= need_full) {
        hipMemsetAsync(cnt, 0, (size_t)n * sizeof(int), stream);
        k_count<<<(E + 255) / 256, 256, 0, stream>>>(edge_rows, cnt, E);
        k_scan<<<1, 1024, 0, stream>>>(cnt, ptr, n);
        hipMemsetAsync(cnt, 0, (size_t)n * sizeof(int), stream);
        k_fill<<<(E + 255) / 256, 256, 0, stream>>>(edge_rows, edge_cols, edge_vals,
                                                    ptr, cnt, col_s, val_s, E);
        k_gather<<<n, 128, 0, stream>>>(HW, ptr, col_s, val_s, bias, out, n);
    } else {
        // atomic-scatter fallback: only needs HW in ws
        k_init_bias<<<((size_t)n * D + 255) / 256, 256, 0, stream>>>(bias, out, n);
        k_scatter<<<(E + 1) / 2, 256, 0, stream>>>(HW, edge_rows, edge_cols, edge_vals, out, E);
        k_relu<<<((size_t)n * D + 255) / 256, 256, 0, stream>>>(out, n);
    }
}

// Round 2
// 195.040 us; speedup vs baseline: 1.8035x; 1.8035x over previous
//
#include <hip/hip_runtime.h>

#define D 128
#define BM 32   // rows per gemm block

// ---------------- GEMM: HW = H @ W  (fp32 vector ALU, LDS-tiled) ----------------
// block: 256 threads; each thread -> 4 rows x 4 cols micro-tile.
// LDS: sW half (64x128 = 32KB) + sH tile (32x128 = 16KB) = 48KB -> 3 blocks/CU.
__global__ __launch_bounds__(256) void k_gemm(const float* __restrict__ H,
                                              const float* __restrict__ W,
                                              float* __restrict__ HW, int n) {
    __shared__ float sW[64 * D];   // one k-half of W
    __shared__ float sH[BM * D];   // 32-row H tile
    const int tid = threadIdx.x;
    const int row0 = blockIdx.x * BM;
    const int j4 = tid & 31;       // float4 column group
    const int rslot = tid >> 5;    // 0..7 -> rows rslot*4 .. rslot*4+3

    const float4* H4 = reinterpret_cast<const float4*>(H);
    const float4* W4 = reinterpret_cast<const float4*>(W);
    float4* sH4 = reinterpret_cast<float4*>(sH);
    float4* sW4 = reinterpret_cast<float4*>(sW);

    // stage H tile: 32 rows x 32 float4
#pragma unroll
    for (int i = tid; i < BM * (D / 4); i += 256) {
        int r = i >> 5, c4 = i & 31;
        int row = row0 + r;
        float4 v = make_float4(0.f, 0.f, 0.f, 0.f);
        if (row < n) v = H4[(size_t)row * (D / 4) + c4];
        sH4[i] = v;
    }

    float4 acc[4];
#pragma unroll
    for (int r = 0; r < 4; ++r) acc[r] = make_float4(0.f, 0.f, 0.f, 0.f);

    for (int kt = 0; kt < 2; ++kt) {
        __syncthreads();
        // stage W half: 64 rows x 32 float4 = 2048 float4
#pragma unroll
        for (int i = tid; i < 64 * (D / 4); i += 256)
            sW4[i] = W4[(size_t)kt * 2048 + i];
        __syncthreads();

#pragma unroll
        for (int kc = 0; kc < 64; kc += 4) {
            float4 w0 = sW4[(kc + 0) * 32 + j4];
            float4 w1 = sW4[(kc + 1) * 32 + j4];
            float4 w2 = sW4[(kc + 2) * 32 + j4];
            float4 w3 = sW4[(kc + 3) * 32 + j4];
#pragma unroll
            for (int r = 0; r < 4; ++r) {
                float4 hh = *reinterpret_cast<const float4*>(
                    &sH[(rslot * 4 + r) * D + kt * 64 + kc]);
                float4 a = acc[r];
                a.x += hh.x * w0.x; a.y += hh.x * w0.y; a.z += hh.x * w0.z; a.w += hh.x * w0.w;
                a.x += hh.y * w1.x; a.y += hh.y * w1.y; a.z += hh.y * w1.z; a.w += hh.y * w1.w;
                a.x += hh.z * w2.x; a.y += hh.z * w2.y; a.z += hh.z * w2.z; a.w += hh.z * w2.w;
                a.x += hh.w * w3.x; a.y += hh.w * w3.y; a.z += hh.w * w3.z; a.w += hh.w * w3.w;
                acc[r] = a;
            }
        }
    }

#pragma unroll
    for (int r = 0; r < 4; ++r) {
        int row = row0 + rslot * 4 + r;
        if (row < n)
            reinterpret_cast<float4*>(HW)[(size_t)row * (D / 4) + j4] = acc[r];
    }
}

// ---------------- CSR build ----------------
__global__ void k_count(const int* __restrict__ rows, int* __restrict__ cnt, int E) {
    int e = blockIdx.x * blockDim.x + threadIdx.x;
    if (e < E) atomicAdd(&cnt[rows[e]], 1);
}

// 3-level scan: block sums -> scan sums -> apply
__global__ __launch_bounds__(256) void k_bsum(const int* __restrict__ cnt,
                                              int* __restrict__ bsum, int n) {
    __shared__ int wsum[4];
    int i = blockIdx.x * 256 + threadIdx.x;
    int v = (i < n) ? cnt[i] : 0;
#pragma unroll
    for (int o = 32; o; o >>= 1) v += __shfl_down(v, o);
    if ((threadIdx.x & 63) == 0) wsum[threadIdx.x >> 6] = v;
    __syncthreads();
    if (threadIdx.x == 0)
        bsum[blockIdx.x] = wsum[0] + wsum[1] + wsum[2] + wsum[3];
}

__global__ __launch_bounds__(256) void k_scan2(const int* __restrict__ bsum,
                                               int* __restrict__ boff,
                                               int* __restrict__ ptr, int nb, int n) {
    __shared__ int wsum[4];
    int tid = threadIdx.x, lane = tid & 63, wid = tid >> 6;
    int v = (tid < nb) ? bsum[tid] : 0;
    int inc = v;
#pragma unroll
    for (int o = 1; o < 64; o <<= 1) { int t = __shfl_up(inc, o); if (lane >= o) inc += t; }
    if (lane == 63) wsum[wid] = inc;
    __syncthreads();
    int wex = 0;
    for (int w = 0; w < wid; ++w) wex += wsum[w];
    if (tid < nb) boff[tid] = wex + inc - v;
    if (tid == 255) ptr[n] = wex + inc;   // grand total
}

__global__ __launch_bounds__(256) void k_apply(const int* __restrict__ cnt,
                                               const int* __restrict__ boff,
                                               int* __restrict__ ptr, int n) {
    __shared__ int wsum[4];
    int i = blockIdx.x * 256 + threadIdx.x;
    int lane = threadIdx.x & 63, wid = threadIdx.x >> 6;
    int v = (i < n) ? cnt[i] : 0;
    int inc = v;
#pragma unroll
    for (int o = 1; o < 64; o <<= 1) { int t = __shfl_up(inc, o); if (lane >= o) inc += t; }
    if (lane == 63) wsum[wid] = inc;
    __syncthreads();
    int wex = 0;
    for (int w = 0; w < wid; ++w) wex += wsum[w];
    if (i < n) ptr[i] = boff[blockIdx.x] + wex + inc - v;
}

// fill: pack (col,val) into int2; consume cnt via atomicSub (no second memset)
__global__ void k_fill(const int* __restrict__ rows, const int* __restrict__ cols,
                       const float* __restrict__ vals, const int* __restrict__ ptr,
                       int* __restrict__ cnt, int2* __restrict__ cv, int E) {
    int e = blockIdx.x * blockDim.x + threadIdx.x;
    if (e < E) {
        int r = rows[e];
        int old = atomicSub(&cnt[r], 1);          // old in [1..count]
        int p = ptr[r] + old - 1;
        cv[p] = make_int2(cols[e], __float_as_int(vals[e]));
    }
}

// ---------------- Gather SpMM + bias + ReLU ----------------
__global__ __launch_bounds__(256) void k_gather(const float* __restrict__ HW,
                                                const int* __restrict__ ptr,
                                                const int2* __restrict__ cv,
                                                const float* __restrict__ bias,
                                                float* __restrict__ out, int n) {
    int r = blockIdx.x * 2 + (threadIdx.x >> 7);
    if (r >= n) return;
    int j = threadIdx.x & 127;
    int s = ptr[r], e = ptr[r + 1];
    float acc = 0.f;
    int t = s;
    for (; t + 4 <= e; t += 4) {
        int2 q0 = cv[t], q1 = cv[t + 1], q2 = cv[t + 2], q3 = cv[t + 3];
        float m0 = HW[(size_t)q0.x * D + j];
        float m1 = HW[(size_t)q1.x * D + j];
        float m2 = HW[(size_t)q2.x * D + j];
        float m3 = HW[(size_t)q3.x * D + j];
        acc += __int_as_float(q0.y) * m0;
        acc += __int_as_float(q1.y) * m1;
        acc += __int_as_float(q2.y) * m2;
        acc += __int_as_float(q3.y) * m3;
    }
    for (; t < e; ++t) {
        int2 q = cv[t];
        acc += __int_as_float(q.y) * HW[(size_t)q.x * D + j];
    }
    out[(size_t)r * D + j] = fmaxf(acc + bias[j], 0.f);
}

// ---------------- Fallback path (small ws): atomic scatter ----------------
__global__ void k_init_bias(const float* __restrict__ bias, float* __restrict__ out, int n) {
    int i = blockIdx.x * blockDim.x + threadIdx.x;
    if (i < n * D) out[i] = bias[i & (D - 1)];
}
__global__ void k_scatter(const float* __restrict__ HW, const int* __restrict__ rows,
                          const int* __restrict__ cols, const float* __restrict__ vals,
                          float* __restrict__ out, int E) {
    int e = blockIdx.x * 2 + (threadIdx.x >> 7);
    int j = threadIdx.x & (D - 1);
    if (e < E) {
        int r = rows[e];
        int c = cols[e];
        float v = vals[e];
        atomicAdd(&out[(size_t)r * D + j], v * HW[(size_t)c * D + j]);
    }
}
__global__ void k_relu(float* __restrict__ out, int n) {
    int i = blockIdx.x * blockDim.x + threadIdx.x;
    if (i < n * D) out[i] = fmaxf(out[i], 0.f);
}

extern "C" void kernel_launch(void* const* d_in, const int* in_sizes, int n_in,
                              void* d_out, int out_size, void* d_ws, size_t ws_size,
                              hipStream_t stream) {
    const float* H         = (const float*)d_in[0];
    const float* W         = (const float*)d_in[1];
    const float* bias      = (const float*)d_in[2];
    const float* edge_vals = (const float*)d_in[3];
    const int*   edge_rows = (const int*)d_in[4];
    const int*   edge_cols = (const int*)d_in[5];
    float* out = (float*)d_out;

    const int n = in_sizes[0] / D;   // 50000
    const int E = in_sizes[3];       // 800000
    const int nb = (n + 255) / 256;  // scan blocks

    char* ws = (char*)d_ws;
    float* HW = (float*)ws;          ws += (size_t)n * D * sizeof(float);
    int* ptr  = (int*)ws;            ws += ((size_t)n + 1) * sizeof(int);
    int* cnt  = (int*)ws;            ws += (size_t)n * sizeof(int);
    int* bsum = (int*)ws;            ws += (size_t)nb * sizeof(int);
    int* boff = (int*)ws;            ws += (size_t)nb * sizeof(int);
    int2* cv  = (int2*)ws;           ws += (size_t)E * sizeof(int2);
    size_t need_full = (size_t)(ws - (char*)d_ws);

    k_gemm<<<(n + BM - 1) / BM, 256, 0, stream>>>(H, W, HW, n);

    if (ws_size >= need_full) {
        hipMemsetAsync(cnt, 0, (size_t)n * sizeof(int), stream);
        k_count<<<(E + 255) / 256, 256, 0, stream>>>(edge_rows, cnt, E);
        k_bsum<<<nb, 256, 0, stream>>>(cnt, bsum, n);
        k_scan2<<<1, 256, 0, stream>>>(bsum, boff, ptr, nb, n);
        k_apply<<<nb, 256, 0, stream>>>(cnt, boff, ptr, n);
        k_fill<<<(E + 255) / 256, 256, 0, stream>>>(edge_rows, edge_cols, edge_vals,
                                                    ptr, cnt, cv, E);
        k_gather<<<(n + 1) / 2, 256, 0, stream>>>(HW, ptr, cv, bias, out, n);
    } else {
        k_init_bias<<<((size_t)n * D + 255) / 256, 256, 0, stream>>>(bias, out, n);
        k_scatter<<<(E + 1) / 2, 256, 0, stream>>>(HW, edge_rows, edge_cols, edge_vals, out, E);
        k_relu<<<((size_t)n * D + 255) / 256, 256, 0, stream>>>(out, n);
    }
}

// Round 3
// 170.062 us; speedup vs baseline: 2.0684x; 1.1469x over previous
//
#include <hip/hip_runtime.h>

#define D 128
#define BM 32   // rows per gemm block

__device__ __forceinline__ unsigned short f2bf(float f) {
    unsigned u = __float_as_uint(f);
    u = (u + 0x7FFFu + ((u >> 16) & 1u)) >> 16;   // RNE
    return (unsigned short)u;
}
__device__ __forceinline__ float bf2f(unsigned short h) {
    return __uint_as_float(((unsigned)h) << 16);
}

// ---------------- GEMM: HWb = bf16(H @ W), fused edge-count histogram ----------------
__global__ __launch_bounds__(256) void k_gemm(const float* __restrict__ H,
                                              const float* __restrict__ W,
                                              unsigned short* __restrict__ HWb,
                                              const int* __restrict__ erows,
                                              int* __restrict__ cnt,
                                              int n, int E, int echunk) {
    __shared__ float sW[64 * D];   // one k-half of W
    __shared__ float sH[BM * D];   // 32-row H tile
    const int tid = threadIdx.x;
    const int row0 = blockIdx.x * BM;
    const int j4 = tid & 31;       // float4 column group
    const int rslot = tid >> 5;    // 0..7

    // fused count: this block's edge chunk
    {
        int base = blockIdx.x * echunk;
        int end = base + echunk; if (end > E) end = E;
        for (int t = base + tid; t < end; t += 256)
            atomicAdd(&cnt[erows[t]], 1);
    }

    const float4* H4 = reinterpret_cast<const float4*>(H);
    const float4* W4 = reinterpret_cast<const float4*>(W);
    float4* sH4 = reinterpret_cast<float4*>(sH);
    float4* sW4 = reinterpret_cast<float4*>(sW);

#pragma unroll
    for (int i = tid; i < BM * (D / 4); i += 256) {
        int r = i >> 5, c4 = i & 31;
        int row = row0 + r;
        float4 v = make_float4(0.f, 0.f, 0.f, 0.f);
        if (row < n) v = H4[(size_t)row * (D / 4) + c4];
        sH4[i] = v;
    }

    float4 acc[4];
#pragma unroll
    for (int r = 0; r < 4; ++r) acc[r] = make_float4(0.f, 0.f, 0.f, 0.f);

    for (int kt = 0; kt < 2; ++kt) {
        __syncthreads();
#pragma unroll
        for (int i = tid; i < 64 * (D / 4); i += 256)
            sW4[i] = W4[(size_t)kt * 2048 + i];
        __syncthreads();

#pragma unroll
        for (int kc = 0; kc < 64; kc += 4) {
            float4 w0 = sW4[(kc + 0) * 32 + j4];
            float4 w1 = sW4[(kc + 1) * 32 + j4];
            float4 w2 = sW4[(kc + 2) * 32 + j4];
            float4 w3 = sW4[(kc + 3) * 32 + j4];
#pragma unroll
            for (int r = 0; r < 4; ++r) {
                float4 hh = *reinterpret_cast<const float4*>(
                    &sH[(rslot * 4 + r) * D + kt * 64 + kc]);
                float4 a = acc[r];
                a.x += hh.x * w0.x; a.y += hh.x * w0.y; a.z += hh.x * w0.z; a.w += hh.x * w0.w;
                a.x += hh.y * w1.x; a.y += hh.y * w1.y; a.z += hh.y * w1.z; a.w += hh.y * w1.w;
                a.x += hh.z * w2.x; a.y += hh.z * w2.y; a.z += hh.z * w2.z; a.w += hh.z * w2.w;
                a.x += hh.w * w3.x; a.y += hh.w * w3.y; a.z += hh.w * w3.z; a.w += hh.w * w3.w;
                acc[r] = a;
            }
        }
    }

#pragma unroll
    for (int r = 0; r < 4; ++r) {
        int row = row0 + rslot * 4 + r;
        if (row < n) {
            ushort4 o;
            o.x = f2bf(acc[r].x); o.y = f2bf(acc[r].y);
            o.z = f2bf(acc[r].z); o.w = f2bf(acc[r].w);
            *reinterpret_cast<ushort4*>(&HWb[(size_t)row * D + j4 * 4]) = o;
        }
    }
}

// ---------------- scan: block sums -> scan sums -> apply ----------------
__global__ __launch_bounds__(256) void k_bsum(const int* __restrict__ cnt,
                                              int* __restrict__ bsum, int n) {
    __shared__ int wsum[4];
    int i = blockIdx.x * 256 + threadIdx.x;
    int v = (i < n) ? cnt[i] : 0;
#pragma unroll
    for (int o = 32; o; o >>= 1) v += __shfl_down(v, o);
    if ((threadIdx.x & 63) == 0) wsum[threadIdx.x >> 6] = v;
    __syncthreads();
    if (threadIdx.x == 0)
        bsum[blockIdx.x] = wsum[0] + wsum[1] + wsum[2] + wsum[3];
}

__global__ __launch_bounds__(256) void k_scan2(const int* __restrict__ bsum,
                                               int* __restrict__ boff,
                                               int* __restrict__ ptr, int nb, int n) {
    __shared__ int wsum[4];
    int tid = threadIdx.x, lane = tid & 63, wid = tid >> 6;
    int v = (tid < nb) ? bsum[tid] : 0;
    int inc = v;
#pragma unroll
    for (int o = 1; o < 64; o <<= 1) { int t = __shfl_up(inc, o); if (lane >= o) inc += t; }
    if (lane == 63) wsum[wid] = inc;
    __syncthreads();
    int wex = 0;
    for (int w = 0; w < wid; ++w) wex += wsum[w];
    if (tid < nb) boff[tid] = wex + inc - v;
    if (tid == 255) ptr[n] = wex + inc;   // grand total = E
}

__global__ __launch_bounds__(256) void k_apply(const int* __restrict__ cnt,
                                               const int* __restrict__ boff,
                                               int* __restrict__ ptr, int n) {
    __shared__ int wsum[4];
    int i = blockIdx.x * 256 + threadIdx.x;
    int lane = threadIdx.x & 63, wid = threadIdx.x >> 6;
    int v = (i < n) ? cnt[i] : 0;
    int inc = v;
#pragma unroll
    for (int o = 1; o < 64; o <<= 1) { int t = __shfl_up(inc, o); if (lane >= o) inc += t; }
    if (lane == 63) wsum[wid] = inc;
    __syncthreads();
    int wex = 0;
    for (int w = 0; w < wid; ++w) wex += wsum[w];
    if (i < n) ptr[i] = boff[blockIdx.x] + wex + inc - v;
}

// fill: pack (col,val) int2; consume cnt via atomicSub
__global__ void k_fill(const int* __restrict__ rows, const int* __restrict__ cols,
                       const float* __restrict__ vals, const int* __restrict__ ptr,
                       int* __restrict__ cnt, int2* __restrict__ cv, int E) {
    int e = blockIdx.x * blockDim.x + threadIdx.x;
    if (e < E) {
        int r = rows[e];
        int old = atomicSub(&cnt[r], 1);          // old in [1..count]
        int p = ptr[r] + old - 1;
        cv[p] = make_int2(cols[e], __float_as_int(vals[e]));
    }
}

// ---------------- Gather SpMM + bias + ReLU : one wave per row ----------------
__global__ __launch_bounds__(256) void k_gather(const unsigned short* __restrict__ HWb,
                                                const int* __restrict__ ptr,
                                                const int2* __restrict__ cv,
                                                const float* __restrict__ bias,
                                                float* __restrict__ out, int n) {
    int r = (blockIdx.x * 256 + threadIdx.x) >> 6;   // wave id = row
    if (r >= n) return;
    int lane = threadIdx.x & 63;
    int s = ptr[r], e = ptr[r + 1];
    float a0 = 0.f, a1 = 0.f;
    const unsigned c2 = 2 * lane;                     // cols c2, c2+1
    int t = s;
    for (; t + 4 <= e; t += 4) {
        int2 q0 = cv[t], q1 = cv[t + 1], q2 = cv[t + 2], q3 = cv[t + 3];
        unsigned m0 = *reinterpret_cast<const unsigned*>(&HWb[(size_t)q0.x * D + c2]);
        unsigned m1 = *reinterpret_cast<const unsigned*>(&HWb[(size_t)q1.x * D + c2]);
        unsigned m2 = *reinterpret_cast<const unsigned*>(&HWb[(size_t)q2.x * D + c2]);
        unsigned m3 = *reinterpret_cast<const unsigned*>(&HWb[(size_t)q3.x * D + c2]);
        float v0 = __int_as_float(q0.y), v1 = __int_as_float(q1.y);
        float v2 = __int_as_float(q2.y), v3 = __int_as_float(q3.y);
        a0 += v0 * bf2f((unsigned short)(m0 & 0xFFFF));
        a1 += v0 * bf2f((unsigned short)(m0 >> 16));
        a0 += v1 * bf2f((unsigned short)(m1 & 0xFFFF));
        a1 += v1 * bf2f((unsigned short)(m1 >> 16));
        a0 += v2 * bf2f((unsigned short)(m2 & 0xFFFF));
        a1 += v2 * bf2f((unsigned short)(m2 >> 16));
        a0 += v3 * bf2f((unsigned short)(m3 & 0xFFFF));
        a1 += v3 * bf2f((unsigned short)(m3 >> 16));
    }
    for (; t < e; ++t) {
        int2 q = cv[t];
        unsigned m = *reinterpret_cast<const unsigned*>(&HWb[(size_t)q.x * D + c2]);
        float v = __int_as_float(q.y);
        a0 += v * bf2f((unsigned short)(m & 0xFFFF));
        a1 += v * bf2f((unsigned short)(m >> 16));
    }
    float2 b = *reinterpret_cast<const float2*>(&bias[c2]);
    float2 o;
    o.x = fmaxf(a0 + b.x, 0.f);
    o.y = fmaxf(a1 + b.y, 0.f);
    *reinterpret_cast<float2*>(&out[(size_t)r * D + c2]) = o;
}

// ---------------- Fallback path (small ws): atomic scatter ----------------
__global__ void k_init_bias(const float* __restrict__ bias, float* __restrict__ out, int n) {
    int i = blockIdx.x * blockDim.x + threadIdx.x;
    if (i < n * D) out[i] = bias[i & (D - 1)];
}
__global__ void k_scatter(const unsigned short* __restrict__ HWb, const int* __restrict__ rows,
                          const int* __restrict__ cols, const float* __restrict__ vals,
                          float* __restrict__ out, int E) {
    int e = blockIdx.x * 2 + (threadIdx.x >> 7);
    int j = threadIdx.x & (D - 1);
    if (e < E) {
        int r = rows[e];
        int c = cols[e];
        float v = vals[e];
        atomicAdd(&out[(size_t)r * D + j], v * bf2f(HWb[(size_t)c * D + j]));
    }
}
__global__ void k_relu(float* __restrict__ out, int n) {
    int i = blockIdx.x * blockDim.x + threadIdx.x;
    if (i < n * D) out[i] = fmaxf(out[i], 0.f);
}

extern "C" void kernel_launch(void* const* d_in, const int* in_sizes, int n_in,
                              void* d_out, int out_size, void* d_ws, size_t ws_size,
                              hipStream_t stream) {
    const float* H         = (const float*)d_in[0];
    const float* W         = (const float*)d_in[1];
    const float* bias      = (const float*)d_in[2];
    const float* edge_vals = (const float*)d_in[3];
    const int*   edge_rows = (const int*)d_in[4];
    const int*   edge_cols = (const int*)d_in[5];
    float* out = (float*)d_out;

    const int n = in_sizes[0] / D;   // 50000
    const int E = in_sizes[3];       // 800000
    const int nb = (n + 255) / 256;  // scan blocks
    const int gblocks = (n + BM - 1) / BM;
    const int echunk = (E + gblocks - 1) / gblocks;

    char* ws = (char*)d_ws;
    unsigned short* HWb = (unsigned short*)ws; ws += (size_t)n * D * sizeof(unsigned short);
    int* ptr  = (int*)ws;            ws += ((size_t)n + 1) * sizeof(int);
    int* cnt  = (int*)ws;            ws += (size_t)n * sizeof(int);
    int* bsum = (int*)ws;            ws += (size_t)nb * sizeof(int);
    int* boff = (int*)ws;            ws += (size_t)nb * sizeof(int);
    int2* cv  = (int2*)ws;           ws += (size_t)E * sizeof(int2);
    size_t need_full = (size_t)(ws - (char*)d_ws);

    hipMemsetAsync(cnt, 0, (size_t)n * sizeof(int), stream);
    k_gemm<<<gblocks, 256, 0, stream>>>(H, W, HWb, edge_rows, cnt, n, E, echunk);

    if (ws_size >= need_full) {
        k_bsum<<<nb, 256, 0, stream>>>(cnt, bsum, n);
        k_scan2<<<1, 256, 0, stream>>>(bsum, boff, ptr, nb, n);
        k_apply<<<nb, 256, 0, stream>>>(cnt, boff, ptr, n);
        k_fill<<<(E + 255) / 256, 256, 0, stream>>>(edge_rows, edge_cols, edge_vals,
                                                    ptr, cnt, cv, E);
        k_gather<<<(n + 3) / 4, 256, 0, stream>>>(HWb, ptr, cv, bias, out, n);
    } else {
        k_init_bias<<<((size_t)n * D + 255) / 256, 256, 0, stream>>>(bias, out, n);
        k_scatter<<<(E + 1) / 2, 256, 0, stream>>>(HWb, edge_rows, edge_cols, edge_vals, out, E);
        k_relu<<<((size_t)n * D + 255) / 256, 256, 0, stream>>>(out, n);
    }
}

// Round 4
// 147.317 us; speedup vs baseline: 2.3877x; 1.1544x over previous
//
#include <hip/hip_runtime.h>

#define D 128
#define BM 64   // rows per gemm block

typedef __attribute__((ext_vector_type(8))) short bf16x8;
typedef __attribute__((ext_vector_type(4))) float f32x4;

__device__ __forceinline__ unsigned short f2bf(float f) {
    unsigned u = __float_as_uint(f);
    u = (u + 0x7FFFu + ((u >> 16) & 1u)) >> 16;   // RNE
    return (unsigned short)u;
}
__device__ __forceinline__ float bf2f(unsigned short h) {
    return __uint_as_float(((unsigned)h) << 16);
}

// ---------------- prep: Wt[n][k] = bf16(W[k][n]) ----------------
__global__ __launch_bounds__(128) void k_prepw(const float* __restrict__ W,
                                               unsigned short* __restrict__ Wt) {
    int n = blockIdx.x, k = threadIdx.x;
    Wt[n * D + k] = f2bf(W[k * D + n]);
}

// ---------------- GEMM: HWb = bf16(bf16(H) @ bf16(W)) via MFMA ----------------
// 256 thr = 4 waves; block tile 64x128; wave tile 16x128 (8 col-tiles x K=128).
// LDS: sA 64x128 bf16 (16KB) + sB 128x128 bf16 (32KB), both chunk-XOR swizzled.
__global__ __launch_bounds__(256) void k_gemm(const float* __restrict__ H,
                                              const unsigned short* __restrict__ Wt,
                                              unsigned short* __restrict__ HWb,
                                              const int* __restrict__ erows,
                                              int* __restrict__ cnt,
                                              int n, int E, int echunk) {
    __shared__ unsigned short sA[BM * D];
    __shared__ unsigned short sB[D * D];
    const int tid = threadIdx.x;
    const int row0 = blockIdx.x * BM;

    // fused edge-count histogram (this block's chunk)
    {
        int base = blockIdx.x * echunk;
        int end = base + echunk; if (end > E) end = E;
        for (int t = base + tid; t < end; t += 256)
            atomicAdd(&cnt[erows[t]], 1);
    }

    // stage Wt -> sB (2048 16B-chunks, 8/thread), swizzle chunk ^= (n&7)
#pragma unroll
    for (int s = 0; s < 8; ++s) {
        int idx = s * 256 + tid;
        int nn = idx >> 4, cc = idx & 15;
        bf16x8 v = *reinterpret_cast<const bf16x8*>(&Wt[(size_t)idx * 8]);
        *reinterpret_cast<bf16x8*>(&sB[nn * D + ((cc ^ (nn & 7)) * 8)]) = v;
    }
    // stage H -> sA (1024 16B-chunks, 4/thread), convert fp32->bf16, same swizzle
#pragma unroll
    for (int s = 0; s < 4; ++s) {
        int idx = s * 256 + tid;
        int r = idx >> 4, cc = idx & 15;
        int row = row0 + r;
        float4 u0 = make_float4(0.f, 0.f, 0.f, 0.f), u1 = u0;
        if (row < n) {
            const float4* p = reinterpret_cast<const float4*>(&H[(size_t)row * D + cc * 8]);
            u0 = p[0]; u1 = p[1];
        }
        bf16x8 v;
        v[0] = (short)f2bf(u0.x); v[1] = (short)f2bf(u0.y);
        v[2] = (short)f2bf(u0.z); v[3] = (short)f2bf(u0.w);
        v[4] = (short)f2bf(u1.x); v[5] = (short)f2bf(u1.y);
        v[6] = (short)f2bf(u1.z); v[7] = (short)f2bf(u1.w);
        *reinterpret_cast<bf16x8*>(&sA[r * D + ((cc ^ (r & 7)) * 8)]) = v;
    }
    __syncthreads();

    const int w = tid >> 6, l = tid & 63;
    const int lr = l & 15, lq = l >> 4;
    f32x4 acc[8];
#pragma unroll
    for (int ct = 0; ct < 8; ++ct) acc[ct] = (f32x4){0.f, 0.f, 0.f, 0.f};

#pragma unroll
    for (int ks = 0; ks < 4; ++ks) {
        const int arow = w * 16 + lr;
        const int acc_c = (ks * 4 + lq) ^ (arow & 7);
        bf16x8 a = *reinterpret_cast<const bf16x8*>(&sA[arow * D + acc_c * 8]);
#pragma unroll
        for (int ct = 0; ct < 8; ++ct) {
            const int brow = ct * 16 + lr;
            const int bcc = (ks * 4 + lq) ^ (brow & 7);
            bf16x8 b = *reinterpret_cast<const bf16x8*>(&sB[brow * D + bcc * 8]);
            acc[ct] = __builtin_amdgcn_mfma_f32_16x16x32_bf16(a, b, acc[ct], 0, 0, 0);
        }
    }

    // epilogue: C/D layout col=lane&15, row=(lane>>4)*4+i  (m89-verified)
#pragma unroll
    for (int ct = 0; ct < 8; ++ct) {
#pragma unroll
        for (int i = 0; i < 4; ++i) {
            int row = row0 + w * 16 + lq * 4 + i;
            int col = ct * 16 + lr;
            if (row < n) HWb[(size_t)row * D + col] = f2bf(acc[ct][i]);
        }
    }
}

// ---------------- scan: block sums -> scan sums -> apply ----------------
__global__ __launch_bounds__(256) void k_bsum(const int* __restrict__ cnt,
                                              int* __restrict__ bsum, int n) {
    __shared__ int wsum[4];
    int i = blockIdx.x * 256 + threadIdx.x;
    int v = (i < n) ? cnt[i] : 0;
#pragma unroll
    for (int o = 32; o; o >>= 1) v += __shfl_down(v, o);
    if ((threadIdx.x & 63) == 0) wsum[threadIdx.x >> 6] = v;
    __syncthreads();
    if (threadIdx.x == 0)
        bsum[blockIdx.x] = wsum[0] + wsum[1] + wsum[2] + wsum[3];
}

__global__ __launch_bounds__(256) void k_scan2(const int* __restrict__ bsum,
                                               int* __restrict__ boff,
                                               int* __restrict__ ptr, int nb, int n) {
    __shared__ int wsum[4];
    int tid = threadIdx.x, lane = tid & 63, wid = tid >> 6;
    int v = (tid < nb) ? bsum[tid] : 0;
    int inc = v;
#pragma unroll
    for (int o = 1; o < 64; o <<= 1) { int t = __shfl_up(inc, o); if (lane >= o) inc += t; }
    if (lane == 63) wsum[wid] = inc;
    __syncthreads();
    int wex = 0;
    for (int w = 0; w < wid; ++w) wex += wsum[w];
    if (tid < nb) boff[tid] = wex + inc - v;
    if (tid == 255) ptr[n] = wex + inc;   // grand total = E
}

__global__ __launch_bounds__(256) void k_apply(const int* __restrict__ cnt,
                                               const int* __restrict__ boff,
                                               int* __restrict__ ptr, int n) {
    __shared__ int wsum[4];
    int i = blockIdx.x * 256 + threadIdx.x;
    int lane = threadIdx.x & 63, wid = threadIdx.x >> 6;
    int v = (i < n) ? cnt[i] : 0;
    int inc = v;
#pragma unroll
    for (int o = 1; o < 64; o <<= 1) { int t = __shfl_up(inc, o); if (lane >= o) inc += t; }
    if (lane == 63) wsum[wid] = inc;
    __syncthreads();
    int wex = 0;
    for (int w = 0; w < wid; ++w) wex += wsum[w];
    if (i < n) ptr[i] = boff[blockIdx.x] + wex + inc - v;
}

// fill: pack (col,val) int2; consume cnt via atomicSub
__global__ void k_fill(const int* __restrict__ rows, const int* __restrict__ cols,
                       const float* __restrict__ vals, const int* __restrict__ ptr,
                       int* __restrict__ cnt, int2* __restrict__ cv, int E) {
    int e = blockIdx.x * blockDim.x + threadIdx.x;
    if (e < E) {
        int r = rows[e];
        int old = atomicSub(&cnt[r], 1);          // old in [1..count]
        int p = ptr[r] + old - 1;
        cv[p] = make_int2(cols[e], __float_as_int(vals[e]));
    }
}

// ---------------- Gather SpMM + bias + ReLU : one wave per row ----------------
__global__ __launch_bounds__(256) void k_gather(const unsigned short* __restrict__ HWb,
                                                const int* __restrict__ ptr,
                                                const int2* __restrict__ cv,
                                                const float* __restrict__ bias,
                                                float* __restrict__ out, int n) {
    int r = (blockIdx.x * 256 + threadIdx.x) >> 6;   // wave id = row
    if (r >= n) return;
    int lane = threadIdx.x & 63;
    int s = ptr[r], e = ptr[r + 1];
    float a0 = 0.f, a1 = 0.f;
    const unsigned c2 = 2 * lane;                     // cols c2, c2+1
    int t = s;
    for (; t + 4 <= e; t += 4) {
        int2 q0 = cv[t], q1 = cv[t + 1], q2 = cv[t + 2], q3 = cv[t + 3];
        unsigned m0 = *reinterpret_cast<const unsigned*>(&HWb[(size_t)q0.x * D + c2]);
        unsigned m1 = *reinterpret_cast<const unsigned*>(&HWb[(size_t)q1.x * D + c2]);
        unsigned m2 = *reinterpret_cast<const unsigned*>(&HWb[(size_t)q2.x * D + c2]);
        unsigned m3 = *reinterpret_cast<const unsigned*>(&HWb[(size_t)q3.x * D + c2]);
        float v0 = __int_as_float(q0.y), v1 = __int_as_float(q1.y);
        float v2 = __int_as_float(q2.y), v3 = __int_as_float(q3.y);
        a0 += v0 * bf2f((unsigned short)(m0 & 0xFFFF));
        a1 += v0 * bf2f((unsigned short)(m0 >> 16));
        a0 += v1 * bf2f((unsigned short)(m1 & 0xFFFF));
        a1 += v1 * bf2f((unsigned short)(m1 >> 16));
        a0 += v2 * bf2f((unsigned short)(m2 & 0xFFFF));
        a1 += v2 * bf2f((unsigned short)(m2 >> 16));
        a0 += v3 * bf2f((unsigned short)(m3 & 0xFFFF));
        a1 += v3 * bf2f((unsigned short)(m3 >> 16));
    }
    for (; t < e; ++t) {
        int2 q = cv[t];
        unsigned m = *reinterpret_cast<const unsigned*>(&HWb[(size_t)q.x * D + c2]);
        float v = __int_as_float(q.y);
        a0 += v * bf2f((unsigned short)(m & 0xFFFF));
        a1 += v * bf2f((unsigned short)(m >> 16));
    }
    float2 b = *reinterpret_cast<const float2*>(&bias[c2]);
    float2 o;
    o.x = fmaxf(a0 + b.x, 0.f);
    o.y = fmaxf(a1 + b.y, 0.f);
    *reinterpret_cast<float2*>(&out[(size_t)r * D + c2]) = o;
}

// ---------------- Fallback path (small ws): atomic scatter ----------------
__global__ void k_init_bias(const float* __restrict__ bias, float* __restrict__ out, int n) {
    int i = blockIdx.x * blockDim.x + threadIdx.x;
    if (i < n * D) out[i] = bias[i & (D - 1)];
}
__global__ void k_scatter(const unsigned short* __restrict__ HWb, const int* __restrict__ rows,
                          const int* __restrict__ cols, const float* __restrict__ vals,
                          float* __restrict__ out, int E) {
    int e = blockIdx.x * 2 + (threadIdx.x >> 7);
    int j = threadIdx.x & (D - 1);
    if (e < E) {
        int r = rows[e];
        int c = cols[e];
        float v = vals[e];
        atomicAdd(&out[(size_t)r * D + j], v * bf2f(HWb[(size_t)c * D + j]));
    }
}
__global__ void k_relu(float* __restrict__ out, int n) {
    int i = blockIdx.x * blockDim.x + threadIdx.x;
    if (i < n * D) out[i] = fmaxf(out[i], 0.f);
}

extern "C" void kernel_launch(void* const* d_in, const int* in_sizes, int n_in,
                              void* d_out, int out_size, void* d_ws, size_t ws_size,
                              hipStream_t stream) {
    const float* H         = (const float*)d_in[0];
    const float* W         = (const float*)d_in[1];
    const float* bias      = (const float*)d_in[2];
    const float* edge_vals = (const float*)d_in[3];
    const int*   edge_rows = (const int*)d_in[4];
    const int*   edge_cols = (const int*)d_in[5];
    float* out = (float*)d_out;

    const int n = in_sizes[0] / D;   // 50000
    const int E = in_sizes[3];       // 800000
    const int nb = (n + 255) / 256;  // scan blocks
    const int gblocks = (n + BM - 1) / BM;
    const int echunk = (E + gblocks - 1) / gblocks;

    char* ws = (char*)d_ws;
    unsigned short* HWb = (unsigned short*)ws; ws += (size_t)n * D * sizeof(unsigned short);
    unsigned short* Wt  = (unsigned short*)ws; ws += (size_t)D * D * sizeof(unsigned short);
    int* ptr  = (int*)ws;            ws += ((size_t)n + 1) * sizeof(int);
    int* cnt  = (int*)ws;            ws += (size_t)n * sizeof(int);
    int* bsum = (int*)ws;            ws += (size_t)nb * sizeof(int);
    int* boff = (int*)ws;            ws += (size_t)nb * sizeof(int);
    int2* cv  = (int2*)ws;           ws += (size_t)E * sizeof(int2);
    size_t need_full = (size_t)(ws - (char*)d_ws);

    k_prepw<<<D, D, 0, stream>>>(W, Wt);

    if (ws_size >= need_full) {
        hipMemsetAsync(cnt, 0, (size_t)n * sizeof(int), stream);
        k_gemm<<<gblocks, 256, 0, stream>>>(H, Wt, HWb, edge_rows, cnt, n, E, echunk);
        k_bsum<<<nb, 256, 0, stream>>>(cnt, bsum, n);
        k_scan2<<<1, 256, 0, stream>>>(bsum, boff, ptr, nb, n);
        k_apply<<<nb, 256, 0, stream>>>(cnt, boff, ptr, n);
        k_fill<<<(E + 255) / 256, 256, 0, stream>>>(edge_rows, edge_cols, edge_vals,
                                                    ptr, cnt, cv, E);
        k_gather<<<(n + 3) / 4, 256, 0, stream>>>(HWb, ptr, cv, bias, out, n);
    } else {
        // fallback: no CSR; histogram disabled via echunk=0
        k_gemm<<<gblocks, 256, 0, stream>>>(H, Wt, HWb, edge_rows, (int*)d_ws, n, E, 0);
        k_init_bias<<<((size_t)n * D + 255) / 256, 256, 0, stream>>>(bias, out, n);
        k_scatter<<<(E + 1) / 2, 256, 0, stream>>>(HWb, edge_rows, edge_cols, edge_vals, out, E);
        k_relu<<<((size_t)n * D + 255) / 256, 256, 0, stream>>>(out, n);
    }
}